// Round 6
// baseline (251.855 us; speedup 1.0000x reference)
//
#include <hip/hip_runtime.h>
#include <hip/hip_bf16.h>
#include <math.h>

#define NN 100000
#define NE 1600000
#define CAP 48          // slots per node (Poisson(16): P(deg>=48) ~ 1e-11)
#define NB 391          // buckets of 256 nodes
#define BCAP 4608       // bucket capacity (mean 4092, ~8 sigma margin)
#define EPB 4096
#define NBLKA ((NE + EPB - 1) / EPB)
#define NPREP ((NN + 63) / 64)
#define PSTR 72         // LDS row stride (shorts) for MFMA A tile

typedef __attribute__((ext_vector_type(8))) short short8;
typedef __attribute__((ext_vector_type(4))) float floatx4;
typedef __attribute__((ext_vector_type(2))) float float2v;

#if __has_builtin(__builtin_elementwise_fma)
#define VFMA(a, b, c) __builtin_elementwise_fma((a), (b), (c))
#else
#define VFMA(a, b, c) ((a) * (b) + (c))
#endif

static __device__ __forceinline__ unsigned short f2bb(float f) {
    __hip_bfloat16 h = __float2bfloat16(f);
    return *(unsigned short*)&h;
}
static __device__ __forceinline__ float hi_f(unsigned u) {   // hs (high 16)
    return __uint_as_float(u & 0xFFFF0000u);
}
static __device__ __forceinline__ float lo_f(unsigned u) {   // xt (low 16)
    return __uint_as_float(u << 16);
}
// packed pairs: element i from uint a,b (hi halves / lo halves as bf16->f32)
static __device__ __forceinline__ float2v hi2(unsigned a, unsigned b) {
    float2v r; r.x = __uint_as_float(a & 0xFFFF0000u);
    r.y = __uint_as_float(b & 0xFFFF0000u); return r;
}
static __device__ __forceinline__ float2v lo2(unsigned a, unsigned b) {
    float2v r; r.x = __uint_as_float(a << 16);
    r.y = __uint_as_float(b << 16); return r;
}

// ---------------- init: bf16 weight panel + gcursor zero (replaces memset) --
// wb[n][k], n in [0,192): rows 0-63 = w1s cols, 64-127 = w1d cols,
// 128-191 = wt cols; laid out so a B-fragment load is one short8 at
// wb[(nt*16+l15)*64 + koff]. 24KB total -> L1-resident in prep.
__global__ __launch_bounds__(256) void init_kernel(
    const float* __restrict__ w1, const float* __restrict__ wt,
    unsigned short* __restrict__ wb, int* __restrict__ gcursor) {
    int t = threadIdx.x;
    if (blockIdx.x == 0) {
        for (int i = t; i < NB; i += 256) gcursor[i] = 0;
    }
    int stride = gridDim.x * 256;
    for (int idx = blockIdx.x * 256 + t; idx < 192 * 64; idx += stride) {
        int k = idx / 192;
        int n = idx - k * 192;
        int nc = n & 63;
        float v = (n < 64)  ? w1[(size_t)k * 64 + nc]
                : (n < 128) ? w1[(size_t)(64 + k) * 64 + nc]
                            : wt[(size_t)k * 64 + nc];
        wb[(size_t)n * 64 + k] = f2bb(v);
    }
}

// ---------------- K1: prep_mfma (blocks 0..NPREP) U bucket (rest) ----------
// prep (v7): rec[n*64+c] = (bf16(x@W1s)<<16) | bf16(x@wt); hd = bf16(x@W1d+b1);
//            pos4[n] = pos row. B fragments now read directly from the
//            global bf16 panel wb (L1-hot) — no Bs staging, LDS 36.9->9.2KB.
// bucket: edges -> per-256-node buckets (two-phase, R2-proven).
__global__ __launch_bounds__(256) void fused_prep_bucket(
    const float* __restrict__ x, const unsigned short* __restrict__ wb,
    const float* __restrict__ b1, const float* __restrict__ pos,
    const int* __restrict__ ei,
    unsigned int* __restrict__ rec, unsigned short* __restrict__ hd,
    float4* __restrict__ pos4, int* __restrict__ gcursor,
    uint2* __restrict__ bucketed) {
    __shared__ __align__(16) unsigned char smem[64 * PSTR * 2];  // 9216 B
    int t = threadIdx.x;
    if (blockIdx.x < NPREP) {
        // ======== prep branch ========
        unsigned short* As = (unsigned short*)smem;
        int nbase = blockIdx.x * 64;
        {
            int r = t & 63;
            int node = nbase + r; if (node >= NN) node = NN - 1;
            const float4* xr = (const float4*)(x + (size_t)node * 64);
#pragma unroll
            for (int i = 0; i < 4; ++i) {
                int s = (t >> 6) + 4 * i;
                float4 v = xr[s];
                ushort4 o = {f2bb(v.x), f2bb(v.y), f2bb(v.z), f2bb(v.w)};
                *(ushort4*)&As[r * PSTR + s * 4] = o;
            }
        }
        if (t < 64) {
            int node = nbase + t;
            if (node < NN)
                pos4[node] = make_float4(pos[node * 3 + 0], pos[node * 3 + 1],
                                         pos[node * 3 + 2], 0.f);
        }
        __syncthreads();
        int lane = t & 63, wave = t >> 6;
        int grp = lane >> 4, l15 = lane & 15;
        floatx4 acc[12] = {};
        int arow = wave * 16 + l15;
#pragma unroll
        for (int ks = 0; ks < 2; ++ks) {
            int koff = ks * 32 + grp * 8;
            short8 a = *(const short8*)&As[arow * PSTR + koff];
#pragma unroll
            for (int nt = 0; nt < 12; ++nt) {
                short8 b = *(const short8*)&wb[(size_t)(nt * 16 + l15) * 64 + koff];
                acc[nt] = __builtin_amdgcn_mfma_f32_16x16x32_bf16(a, b, acc[nt], 0, 0, 0);
            }
        }
        // tiles 0-3: hs (hi of rec) | tiles 8-11: xt (lo of rec) | 4-7: hd
#pragma unroll
        for (int nt = 0; nt < 4; ++nt) {
#pragma unroll
            for (int r = 0; r < 4; ++r) {
                int nr = wave * 16 + grp * 4 + r;
                int node = nbase + nr;
                if (node >= NN) continue;
                int col = nt * 16 + l15;
                rec[(size_t)node * 64 + col] =
                    ((unsigned)f2bb(acc[nt][r]) << 16) | f2bb(acc[8 + nt][r]);
                hd[(size_t)node * 64 + col] = f2bb(acc[4 + nt][r] + b1[col]);
            }
        }
    } else {
        // ======== bucket branch ========
        int* cnt = (int*)smem;
        int* base_s = cnt + NB;
        for (int i = t; i < NB; i += 256) cnt[i] = 0;
        __syncthreads();
        int e0 = (blockIdx.x - NPREP) * EPB;
        unsigned int tags[16];
        int srcs[16], dsts[16];
#pragma unroll
        for (int i = 0; i < 16; ++i) {
            int e = e0 + i * 256 + t;
            tags[i] = 0xFFFFFFFFu;
            if (e < NE) {
                srcs[i] = ei[e];
                dsts[i] = ei[NE + e];
                int b = dsts[i] >> 8;
                int slot = atomicAdd(&cnt[b], 1);
                tags[i] = ((unsigned)b << 12) | (unsigned)slot;
            }
        }
        __syncthreads();
        for (int b = t; b < NB; b += 256)
            base_s[b] = atomicAdd(&gcursor[b], cnt[b]);
        __syncthreads();
#pragma unroll
        for (int i = 0; i < 16; ++i) {
            if (tags[i] != 0xFFFFFFFFu) {
                int e = e0 + i * 256 + t;
                int b = (int)(tags[i] >> 12);
                int slot = (int)(tags[i] & 0xFFFu);
                int p = base_s[b] + slot;
                if (p < BCAP) {
                    bucketed[(size_t)b * BCAP + p] =
                        make_uint2((unsigned)srcs[i] |
                                   (((unsigned)dsts[i] & 255u) << 17),
                                   (unsigned)e);
                }
            }
        }
    }
}

// ---------------- pass B: per-bucket CSR build, cursors in LDS ----------------
__global__ __launch_bounds__(1024) void csr_kernel(
    const uint2* __restrict__ bucketed, const int* __restrict__ gcursor,
    uint2* __restrict__ pairs, int* __restrict__ deg) {
    __shared__ int cur[256];
    int t = threadIdx.x;
    if (t < 256) cur[t] = 0;
    __syncthreads();
    int b = blockIdx.x;
    int n0 = b << 8;
    int cnt = gcursor[b];
    if (cnt > BCAP) cnt = BCAP;
    for (int i = t; i < cnt; i += 1024) {
        uint2 en = bucketed[(size_t)b * BCAP + i];
        int dwb = (int)((en.x >> 17) & 255u);
        unsigned src = en.x & 0x1FFFFu;
        int slot = atomicAdd(&cur[dwb], 1);
        if (slot < CAP)
            pairs[(size_t)(n0 + dwb) * CAP + slot] = make_uint2(src, en.y);
    }
    __syncthreads();
    if (t < 256) {
        int node = n0 + t;
        if (node < NN) deg[node] = (cur[t] > CAP) ? CAP : cur[t];
    }
}

// ---------------- mega: ew + aggregation + output, 8-edge batches ----------
// wave per node; e8 = lane>>3 (edge of batch), hg = lane&7 (8 hidden units).
// v6 (unchanged, proven): depth-1 pipeline + packed f32 + unroll 2; writes
// out[node] = sum(ew*xt_src) + sw*bt directly.
__global__ __launch_bounds__(256) void mega_kernel(
    const uint2* __restrict__ pairs, const int* __restrict__ deg,
    const unsigned int* __restrict__ rec, const unsigned short* __restrict__ hd,
    const float4* __restrict__ pos4, const float* __restrict__ w1,
    const float* __restrict__ w2, const float* __restrict__ b2,
    const float* __restrict__ bt,
    float* __restrict__ ew_out, float* __restrict__ out) {
    int t = threadIdx.x;
    int w = t >> 6, lane = t & 63;
    int e8 = lane >> 3, hg = lane & 7;
    int node = blockIdx.x * 4 + w;
    if (node >= NN) return;

    const float2v zero2 = {0.f, 0.f};
    float2v a01 = zero2, a23 = zero2, a45 = zero2, a67 = zero2;
    float sw = 0.f;
    int d = deg[node];
    uint4 hz = ((const uint4*)(hd + (size_t)node * 64))[hg];  // 8 bf16
    float2v zb01 = {lo_f(hz.x), hi_f(hz.x)};
    float2v zb23 = {lo_f(hz.y), hi_f(hz.y)};
    float2v zb45 = {lo_f(hz.z), hi_f(hz.z)};
    float2v zb67 = {lo_f(hz.w), hi_f(hz.w)};
    const float2v* w2p = (const float2v*)(w2 + 8 * hg);
    float2v w20 = w2p[0], w21 = w2p[1], w22 = w2p[2], w23 = w2p[3];
    const float2v* wlp = (const float2v*)(w1 + 128 * 64 + 8 * hg);
    float2v wl0 = wlp[0], wl1 = wlp[1], wl2 = wlp[2], wl3 = wlp[3];
    float4 bta = ((const float4*)bt)[2 * hg];
    float4 btb = ((const float4*)bt)[2 * hg + 1];
    float4 pd = pos4[node];
    float b2v = b2[0];
    const uint2* seg = pairs + (size_t)node * CAP;
    const uint4* rec4 = (const uint4*)rec;

    if (d > 0) {
        int i0 = (e8 < d) ? e8 : (d - 1);
        uint2 pr_c = seg[i0];
        uint2 pr_n = pr_c;
        if (8 < d) { int i1 = (8 + e8 < d) ? (8 + e8) : (d - 1); pr_n = seg[i1]; }
        uint4 ua_c = rec4[(size_t)pr_c.x * 16 + 2 * hg];
        uint4 ub_c = rec4[(size_t)pr_c.x * 16 + 2 * hg + 1];
        float4 ps_c = pos4[pr_c.x];

#pragma unroll 2
        for (int j = 0; j < d; j += 8) {
            int jn = j + 8;
            uint2 pr_n2 = pr_n;
            uint4 ua_n = ua_c, ub_n = ub_c;
            float4 ps_n = ps_c;
            if (jn < d) {                        // wave-uniform
                ua_n = rec4[(size_t)pr_n.x * 16 + 2 * hg];
                ub_n = rec4[(size_t)pr_n.x * 16 + 2 * hg + 1];
                ps_n = pos4[pr_n.x];
                if (jn + 8 < d) {
                    int i2 = (jn + 8 + e8 < d) ? (jn + 8 + e8) : (d - 1);
                    pr_n2 = seg[i2];
                }
            }
            bool valid = (j + e8 < d);
            float dx = pd.x - ps_c.x;
            float dy = pd.y - ps_c.y;
            float dz = pd.z - ps_c.z;
            float len = __builtin_amdgcn_sqrtf(dx * dx + dy * dy + dz * dz);
            float2v l2; l2.x = len; l2.y = len;
            // MLP: z = zb + hs + len*wl; tt = sum relu(z)*w2  (packed f32)
            float2v z, r, tp;
            z = zb01 + hi2(ua_c.x, ua_c.y); z = VFMA(l2, wl0, z);
            r = __builtin_elementwise_max(z, zero2); tp = r * w20;
            z = zb23 + hi2(ua_c.z, ua_c.w); z = VFMA(l2, wl1, z);
            r = __builtin_elementwise_max(z, zero2); tp = VFMA(r, w21, tp);
            z = zb45 + hi2(ub_c.x, ub_c.y); z = VFMA(l2, wl2, z);
            r = __builtin_elementwise_max(z, zero2); tp = VFMA(r, w22, tp);
            z = zb67 + hi2(ub_c.z, ub_c.w); z = VFMA(l2, wl3, z);
            r = __builtin_elementwise_max(z, zero2); tp = VFMA(r, w23, tp);
            float tt = tp.x + tp.y;
            tt += __shfl_xor(tt, 1);
            tt += __shfl_xor(tt, 2);
            tt += __shfl_xor(tt, 4);
            float ew = __builtin_amdgcn_rcpf(1.f + __expf(-(tt + b2v)));
            if (valid) {
                if (hg == 0) ew_out[pr_c.y] = ew;
                float2v e2; e2.x = ew; e2.y = ew;
                a01 = VFMA(e2, lo2(ua_c.x, ua_c.y), a01);   // xt_src
                a23 = VFMA(e2, lo2(ua_c.z, ua_c.w), a23);
                a45 = VFMA(e2, lo2(ub_c.x, ub_c.y), a45);
                a67 = VFMA(e2, lo2(ub_c.z, ub_c.w), a67);
                sw += ew;
            }
            pr_c = pr_n; pr_n = pr_n2;
            ua_c = ua_n; ub_c = ub_n; ps_c = ps_n;
        }
    }
    float acc0 = a01.x, acc1 = a01.y, acc2 = a23.x, acc3 = a23.y;
    float acc4 = a45.x, acc5 = a45.y, acc6 = a67.x, acc7 = a67.y;
#pragma unroll
    for (int off = 8; off < 64; off <<= 1) {
        acc0 += __shfl_xor(acc0, off);
        acc1 += __shfl_xor(acc1, off);
        acc2 += __shfl_xor(acc2, off);
        acc3 += __shfl_xor(acc3, off);
        acc4 += __shfl_xor(acc4, off);
        acc5 += __shfl_xor(acc5, off);
        acc6 += __shfl_xor(acc6, off);
        acc7 += __shfl_xor(acc7, off);
        sw   += __shfl_xor(sw, off);
    }
    if (e8 == 0) {
        float* orow = out + (size_t)node * 64 + hg * 8;
        float4 o1 = {acc0 + sw * bta.x, acc1 + sw * bta.y,
                     acc2 + sw * bta.z, acc3 + sw * bta.w};
        float4 o2 = {acc4 + sw * btb.x, acc5 + sw * btb.y,
                     acc6 + sw * btb.z, acc7 + sw * btb.w};
        *(float4*)orow = o1;
        *(float4*)(orow + 4) = o2;
    }
}

extern "C" void kernel_launch(void* const* d_in, const int* in_sizes, int n_in,
                              void* d_out, int out_size, void* d_ws, size_t ws_size,
                              hipStream_t stream) {
    const float* x   = (const float*)d_in[0];
    const int*   ei  = (const int*)d_in[1];
    const float* pos = (const float*)d_in[2];
    const float* w1  = (const float*)d_in[3];
    const float* b1  = (const float*)d_in[4];
    const float* w2  = (const float*)d_in[5];
    const float* b2  = (const float*)d_in[6];
    const float* wt  = (const float*)d_in[7];
    const float* bt  = (const float*)d_in[8];

    float* out    = (float*)d_out;            // [NN*64]
    float* ew_out = out + (size_t)NN * 64;    // [NE]

    // workspace: rec 25.6MB | hd(bf16) 12.8MB | pairs 38.4MB | pos4 1.6MB |
    // gcursor | deg 0.4MB | wb 24KB   (~79MB)
    unsigned int* rec = (unsigned int*)d_ws;
    unsigned short* hd = (unsigned short*)(rec + (size_t)NN * 64);
    uint2* pairs = (uint2*)(hd + (size_t)NN * 64);
    float4* pos4 = (float4*)(pairs + (size_t)NN * CAP);
    int* gcursor = (int*)(pos4 + NN);
    int* deg = gcursor + NB;
    unsigned short* wb = (unsigned short*)(deg + NN);

    // bucketed scratch in d_out[0 .. 14.4MB); consumed by csr_kernel before
    // ew_out (at 25.6MB offset) and out (written by mega last) are produced.
    uint2* bucketed = (uint2*)d_out;

    init_kernel<<<16, 256, 0, stream>>>(w1, wt, wb, gcursor);
    fused_prep_bucket<<<NPREP + NBLKA, 256, 0, stream>>>(
        x, wb, b1, pos, ei, rec, hd, pos4, gcursor, bucketed);
    csr_kernel<<<NB, 1024, 0, stream>>>(bucketed, gcursor, pairs, deg);
    mega_kernel<<<(NN + 3) / 4, 256, 0, stream>>>(pairs, deg, rec, hd, pos4,
                                                  w1, w2, b2, bt, ew_out, out);
}

// Round 7
// 236.563 us; speedup vs baseline: 1.0646x; 1.0646x over previous
//
#include <hip/hip_runtime.h>
#include <hip/hip_bf16.h>
#include <math.h>

#define NN 100000
#define NE 1600000
#define CAP 48          // slots per node (Poisson(16): P(deg>=48) ~ 1e-11)
#define NB 391          // buckets of 256 nodes
#define BCAP 4608       // bucket capacity (mean 4092, ~8 sigma margin)
#define EPB 4096
#define NBLKA ((NE + EPB - 1) / EPB)
#define NPREP ((NN + 63) / 64)
#define PSTR 72         // LDS row stride (shorts) for MFMA tiles

typedef __attribute__((ext_vector_type(8))) short short8;
typedef __attribute__((ext_vector_type(4))) float floatx4;
typedef __attribute__((ext_vector_type(2))) float float2v;

#if __has_builtin(__builtin_elementwise_fma)
#define VFMA(a, b, c) __builtin_elementwise_fma((a), (b), (c))
#else
#define VFMA(a, b, c) ((a) * (b) + (c))
#endif

static __device__ __forceinline__ unsigned short f2bb(float f) {
    __hip_bfloat16 h = __float2bfloat16(f);
    return *(unsigned short*)&h;
}
static __device__ __forceinline__ float hi_f(unsigned u) {   // hs (high 16)
    return __uint_as_float(u & 0xFFFF0000u);
}
static __device__ __forceinline__ float lo_f(unsigned u) {   // xt (low 16)
    return __uint_as_float(u << 16);
}
// packed pairs: element i from uint a,b (hi halves / lo halves as bf16->f32)
static __device__ __forceinline__ float2v hi2(unsigned a, unsigned b) {
    float2v r; r.x = __uint_as_float(a & 0xFFFF0000u);
    r.y = __uint_as_float(b & 0xFFFF0000u); return r;
}
static __device__ __forceinline__ float2v lo2(unsigned a, unsigned b) {
    float2v r; r.x = __uint_as_float(a << 16);
    r.y = __uint_as_float(b << 16); return r;
}

// ---------------- init: bf16 weight panel + gcursor zero (replaces memset) --
// wb[n][k], n in [0,192): rows 0-63 = w1s cols, 64-127 = w1d cols,
// 128-191 = wt cols. wb[n*64+k] = W[k][n-part]. Contiguous 24KB so prep can
// stage it into LDS with coalesced uint4 loads (the R5 staging was 256B-
// strided f32 loads = ~12K L1 transactions/block; this is ~96).
__global__ __launch_bounds__(256) void init_kernel(
    const float* __restrict__ w1, const float* __restrict__ wt,
    unsigned short* __restrict__ wb, int* __restrict__ gcursor) {
    int t = threadIdx.x;
    if (blockIdx.x == 0) {
        for (int i = t; i < NB; i += 256) gcursor[i] = 0;
    }
    int stride = gridDim.x * 256;
    for (int idx = blockIdx.x * 256 + t; idx < 192 * 64; idx += stride) {
        int n = idx >> 6;
        int k = idx & 63;
        float v = (n < 64)  ? w1[(size_t)k * 64 + n]
                : (n < 128) ? w1[(size_t)(64 + k) * 64 + (n - 64)]
                            : wt[(size_t)k * 64 + (n - 128)];
        wb[idx] = f2bb(v);   // coalesced write
    }
}

// ---------------- K1: prep_mfma (blocks 0..NPREP) U bucket (rest) ----------
// prep (v8): rec[n*64+c] = (bf16(x@W1s)<<16) | bf16(x@wt); hd = bf16(x@W1d+b1);
//            pos4[n] = pos row. Bs staged from the bf16 panel wb via
//            coalesced uint4 loads into padded LDS [192][72]; MFMA loop and
//            epilogue identical to R5 (bit-identical outputs).
// bucket: edges -> per-256-node buckets (two-phase, R2-proven).
__global__ __launch_bounds__(256) void fused_prep_bucket(
    const float* __restrict__ x, const unsigned short* __restrict__ wb,
    const float* __restrict__ b1, const float* __restrict__ pos,
    const int* __restrict__ ei,
    unsigned int* __restrict__ rec, unsigned short* __restrict__ hd,
    float4* __restrict__ pos4, int* __restrict__ gcursor,
    uint2* __restrict__ bucketed) {
    __shared__ __align__(16) unsigned char smem[(64 + 192) * PSTR * 2];
    int t = threadIdx.x;
    if (blockIdx.x < NPREP) {
        // ======== prep branch ========
        unsigned short* As = (unsigned short*)smem;
        unsigned short* Bs = As + 64 * PSTR;   // [192][PSTR]
        int nbase = blockIdx.x * 64;
        {
            int r = t & 63;
            int node = nbase + r; if (node >= NN) node = NN - 1;
            const float4* xr = (const float4*)(x + (size_t)node * 64);
#pragma unroll
            for (int i = 0; i < 4; ++i) {
                int s = (t >> 6) + 4 * i;
                float4 v = xr[s];
                ushort4 o = {f2bb(v.x), f2bb(v.y), f2bb(v.z), f2bb(v.w)};
                *(ushort4*)&As[r * PSTR + s * 4] = o;
            }
        }
        {
            // coalesced panel stage: 1536 uint4; thread t takes v = t + 256*i
            const uint4* wb4 = (const uint4*)wb;
#pragma unroll
            for (int i = 0; i < 6; ++i) {
                int v = t + 256 * i;            // uint4 index (8 shorts)
                uint4 q = wb4[v];
                int n = v >> 3;
                int k = (v & 7) * 8;
                *(uint4*)&Bs[n * PSTR + k] = q;
            }
        }
        if (t < 64) {
            int node = nbase + t;
            if (node < NN)
                pos4[node] = make_float4(pos[node * 3 + 0], pos[node * 3 + 1],
                                         pos[node * 3 + 2], 0.f);
        }
        __syncthreads();
        int lane = t & 63, wave = t >> 6;
        int grp = lane >> 4, l15 = lane & 15;
        floatx4 acc[12] = {};
        int arow = wave * 16 + l15;
#pragma unroll
        for (int ks = 0; ks < 2; ++ks) {
            int koff = ks * 32 + grp * 8;
            short8 a = *(const short8*)&As[arow * PSTR + koff];
#pragma unroll
            for (int nt = 0; nt < 12; ++nt) {
                short8 b = *(const short8*)&Bs[(nt * 16 + l15) * PSTR + koff];
                acc[nt] = __builtin_amdgcn_mfma_f32_16x16x32_bf16(a, b, acc[nt], 0, 0, 0);
            }
        }
        // tiles 0-3: hs (hi of rec) | tiles 8-11: xt (lo of rec) | 4-7: hd
#pragma unroll
        for (int nt = 0; nt < 4; ++nt) {
#pragma unroll
            for (int r = 0; r < 4; ++r) {
                int nr = wave * 16 + grp * 4 + r;
                int node = nbase + nr;
                if (node >= NN) continue;
                int col = nt * 16 + l15;
                rec[(size_t)node * 64 + col] =
                    ((unsigned)f2bb(acc[nt][r]) << 16) | f2bb(acc[8 + nt][r]);
                hd[(size_t)node * 64 + col] = f2bb(acc[4 + nt][r] + b1[col]);
            }
        }
    } else {
        // ======== bucket branch ========
        int* cnt = (int*)smem;
        int* base_s = cnt + NB;
        for (int i = t; i < NB; i += 256) cnt[i] = 0;
        __syncthreads();
        int e0 = (blockIdx.x - NPREP) * EPB;
        unsigned int tags[16];
        int srcs[16], dsts[16];
#pragma unroll
        for (int i = 0; i < 16; ++i) {
            int e = e0 + i * 256 + t;
            tags[i] = 0xFFFFFFFFu;
            if (e < NE) {
                srcs[i] = ei[e];
                dsts[i] = ei[NE + e];
                int b = dsts[i] >> 8;
                int slot = atomicAdd(&cnt[b], 1);
                tags[i] = ((unsigned)b << 12) | (unsigned)slot;
            }
        }
        __syncthreads();
        for (int b = t; b < NB; b += 256)
            base_s[b] = atomicAdd(&gcursor[b], cnt[b]);
        __syncthreads();
#pragma unroll
        for (int i = 0; i < 16; ++i) {
            if (tags[i] != 0xFFFFFFFFu) {
                int e = e0 + i * 256 + t;
                int b = (int)(tags[i] >> 12);
                int slot = (int)(tags[i] & 0xFFFu);
                int p = base_s[b] + slot;
                if (p < BCAP) {
                    bucketed[(size_t)b * BCAP + p] =
                        make_uint2((unsigned)srcs[i] |
                                   (((unsigned)dsts[i] & 255u) << 17),
                                   (unsigned)e);
                }
            }
        }
    }
}

// ---------------- pass B: per-bucket CSR build, cursors in LDS ----------------
__global__ __launch_bounds__(1024) void csr_kernel(
    const uint2* __restrict__ bucketed, const int* __restrict__ gcursor,
    uint2* __restrict__ pairs, int* __restrict__ deg) {
    __shared__ int cur[256];
    int t = threadIdx.x;
    if (t < 256) cur[t] = 0;
    __syncthreads();
    int b = blockIdx.x;
    int n0 = b << 8;
    int cnt = gcursor[b];
    if (cnt > BCAP) cnt = BCAP;
    for (int i = t; i < cnt; i += 1024) {
        uint2 en = bucketed[(size_t)b * BCAP + i];
        int dwb = (int)((en.x >> 17) & 255u);
        unsigned src = en.x & 0x1FFFFu;
        int slot = atomicAdd(&cur[dwb], 1);
        if (slot < CAP)
            pairs[(size_t)(n0 + dwb) * CAP + slot] = make_uint2(src, en.y);
    }
    __syncthreads();
    if (t < 256) {
        int node = n0 + t;
        if (node < NN) deg[node] = (cur[t] > CAP) ? CAP : cur[t];
    }
}

// ---------------- mega: ew + aggregation + output, 8-edge batches ----------
// wave per node; e8 = lane>>3 (edge of batch), hg = lane&7 (8 hidden units).
// unchanged from R5 (proven): depth-1 pipeline + packed f32 + unroll 2;
// writes out[node] = sum(ew*xt_src) + sw*bt directly.
__global__ __launch_bounds__(256) void mega_kernel(
    const uint2* __restrict__ pairs, const int* __restrict__ deg,
    const unsigned int* __restrict__ rec, const unsigned short* __restrict__ hd,
    const float4* __restrict__ pos4, const float* __restrict__ w1,
    const float* __restrict__ w2, const float* __restrict__ b2,
    const float* __restrict__ bt,
    float* __restrict__ ew_out, float* __restrict__ out) {
    int t = threadIdx.x;
    int w = t >> 6, lane = t & 63;
    int e8 = lane >> 3, hg = lane & 7;
    int node = blockIdx.x * 4 + w;
    if (node >= NN) return;

    const float2v zero2 = {0.f, 0.f};
    float2v a01 = zero2, a23 = zero2, a45 = zero2, a67 = zero2;
    float sw = 0.f;
    int d = deg[node];
    uint4 hz = ((const uint4*)(hd + (size_t)node * 64))[hg];  // 8 bf16
    float2v zb01 = {lo_f(hz.x), hi_f(hz.x)};
    float2v zb23 = {lo_f(hz.y), hi_f(hz.y)};
    float2v zb45 = {lo_f(hz.z), hi_f(hz.z)};
    float2v zb67 = {lo_f(hz.w), hi_f(hz.w)};
    const float2v* w2p = (const float2v*)(w2 + 8 * hg);
    float2v w20 = w2p[0], w21 = w2p[1], w22 = w2p[2], w23 = w2p[3];
    const float2v* wlp = (const float2v*)(w1 + 128 * 64 + 8 * hg);
    float2v wl0 = wlp[0], wl1 = wlp[1], wl2 = wlp[2], wl3 = wlp[3];
    float4 bta = ((const float4*)bt)[2 * hg];
    float4 btb = ((const float4*)bt)[2 * hg + 1];
    float4 pd = pos4[node];
    float b2v = b2[0];
    const uint2* seg = pairs + (size_t)node * CAP;
    const uint4* rec4 = (const uint4*)rec;

    if (d > 0) {
        int i0 = (e8 < d) ? e8 : (d - 1);
        uint2 pr_c = seg[i0];
        uint2 pr_n = pr_c;
        if (8 < d) { int i1 = (8 + e8 < d) ? (8 + e8) : (d - 1); pr_n = seg[i1]; }
        uint4 ua_c = rec4[(size_t)pr_c.x * 16 + 2 * hg];
        uint4 ub_c = rec4[(size_t)pr_c.x * 16 + 2 * hg + 1];
        float4 ps_c = pos4[pr_c.x];

#pragma unroll 2
        for (int j = 0; j < d; j += 8) {
            int jn = j + 8;
            uint2 pr_n2 = pr_n;
            uint4 ua_n = ua_c, ub_n = ub_c;
            float4 ps_n = ps_c;
            if (jn < d) {                        // wave-uniform
                ua_n = rec4[(size_t)pr_n.x * 16 + 2 * hg];
                ub_n = rec4[(size_t)pr_n.x * 16 + 2 * hg + 1];
                ps_n = pos4[pr_n.x];
                if (jn + 8 < d) {
                    int i2 = (jn + 8 + e8 < d) ? (jn + 8 + e8) : (d - 1);
                    pr_n2 = seg[i2];
                }
            }
            bool valid = (j + e8 < d);
            float dx = pd.x - ps_c.x;
            float dy = pd.y - ps_c.y;
            float dz = pd.z - ps_c.z;
            float len = __builtin_amdgcn_sqrtf(dx * dx + dy * dy + dz * dz);
            float2v l2; l2.x = len; l2.y = len;
            // MLP: z = zb + hs + len*wl; tt = sum relu(z)*w2  (packed f32)
            float2v z, r, tp;
            z = zb01 + hi2(ua_c.x, ua_c.y); z = VFMA(l2, wl0, z);
            r = __builtin_elementwise_max(z, zero2); tp = r * w20;
            z = zb23 + hi2(ua_c.z, ua_c.w); z = VFMA(l2, wl1, z);
            r = __builtin_elementwise_max(z, zero2); tp = VFMA(r, w21, tp);
            z = zb45 + hi2(ub_c.x, ub_c.y); z = VFMA(l2, wl2, z);
            r = __builtin_elementwise_max(z, zero2); tp = VFMA(r, w22, tp);
            z = zb67 + hi2(ub_c.z, ub_c.w); z = VFMA(l2, wl3, z);
            r = __builtin_elementwise_max(z, zero2); tp = VFMA(r, w23, tp);
            float tt = tp.x + tp.y;
            tt += __shfl_xor(tt, 1);
            tt += __shfl_xor(tt, 2);
            tt += __shfl_xor(tt, 4);
            float ew = __builtin_amdgcn_rcpf(1.f + __expf(-(tt + b2v)));
            if (valid) {
                if (hg == 0) ew_out[pr_c.y] = ew;
                float2v e2; e2.x = ew; e2.y = ew;
                a01 = VFMA(e2, lo2(ua_c.x, ua_c.y), a01);   // xt_src
                a23 = VFMA(e2, lo2(ua_c.z, ua_c.w), a23);
                a45 = VFMA(e2, lo2(ub_c.x, ub_c.y), a45);
                a67 = VFMA(e2, lo2(ub_c.z, ub_c.w), a67);
                sw += ew;
            }
            pr_c = pr_n; pr_n = pr_n2;
            ua_c = ua_n; ub_c = ub_n; ps_c = ps_n;
        }
    }
    float acc0 = a01.x, acc1 = a01.y, acc2 = a23.x, acc3 = a23.y;
    float acc4 = a45.x, acc5 = a45.y, acc6 = a67.x, acc7 = a67.y;
#pragma unroll
    for (int off = 8; off < 64; off <<= 1) {
        acc0 += __shfl_xor(acc0, off);
        acc1 += __shfl_xor(acc1, off);
        acc2 += __shfl_xor(acc2, off);
        acc3 += __shfl_xor(acc3, off);
        acc4 += __shfl_xor(acc4, off);
        acc5 += __shfl_xor(acc5, off);
        acc6 += __shfl_xor(acc6, off);
        acc7 += __shfl_xor(acc7, off);
        sw   += __shfl_xor(sw, off);
    }
    if (e8 == 0) {
        float* orow = out + (size_t)node * 64 + hg * 8;
        float4 o1 = {acc0 + sw * bta.x, acc1 + sw * bta.y,
                     acc2 + sw * bta.z, acc3 + sw * bta.w};
        float4 o2 = {acc4 + sw * btb.x, acc5 + sw * btb.y,
                     acc6 + sw * btb.z, acc7 + sw * btb.w};
        *(float4*)orow = o1;
        *(float4*)(orow + 4) = o2;
    }
}

extern "C" void kernel_launch(void* const* d_in, const int* in_sizes, int n_in,
                              void* d_out, int out_size, void* d_ws, size_t ws_size,
                              hipStream_t stream) {
    const float* x   = (const float*)d_in[0];
    const int*   ei  = (const int*)d_in[1];
    const float* pos = (const float*)d_in[2];
    const float* w1  = (const float*)d_in[3];
    const float* b1  = (const float*)d_in[4];
    const float* w2  = (const float*)d_in[5];
    const float* b2  = (const float*)d_in[6];
    const float* wt  = (const float*)d_in[7];
    const float* bt  = (const float*)d_in[8];

    float* out    = (float*)d_out;            // [NN*64]
    float* ew_out = out + (size_t)NN * 64;    // [NE]

    // workspace: rec 25.6MB | hd(bf16) 12.8MB | pairs 38.4MB | pos4 1.6MB |
    // gcursor | deg 0.4MB | wb 24KB   (~79MB)
    unsigned int* rec = (unsigned int*)d_ws;
    unsigned short* hd = (unsigned short*)(rec + (size_t)NN * 64);
    uint2* pairs = (uint2*)(hd + (size_t)NN * 64);
    float4* pos4 = (float4*)(pairs + (size_t)NN * CAP);
    int* gcursor = (int*)(pos4 + NN);
    int* deg = gcursor + NB;
    unsigned short* wb = (unsigned short*)(deg + NN);

    // bucketed scratch in d_out[0 .. 14.4MB); consumed by csr_kernel before
    // ew_out (at 25.6MB offset) and out (written by mega last) are produced.
    uint2* bucketed = (uint2*)d_out;

    init_kernel<<<16, 256, 0, stream>>>(w1, wt, wb, gcursor);
    fused_prep_bucket<<<NPREP + NBLKA, 256, 0, stream>>>(
        x, wb, b1, pos, ei, rec, hd, pos4, gcursor, bucketed);
    csr_kernel<<<NB, 1024, 0, stream>>>(bucketed, gcursor, pairs, deg);
    mega_kernel<<<(NN + 3) / 4, 256, 0, stream>>>(pairs, deg, rec, hd, pos4,
                                                  w1, w2, b2, bt, ew_out, out);
}